// Round 8
// baseline (1360.895 us; speedup 1.0000x reference)
//
#include <hip/hip_runtime.h>
#include <hip/hip_bf16.h>

#define NPTS   8192
#define NBATCH 8
#define S      1024
#define K      16
#define D      64
#define CIN    67
#define WN     16
#define OUTC   128

// d_out layout (floats): [0,24576) new_xyz [B,3,S]; [24576, 24576+1048576) out [B,128,S];
// [1073152, 1081344) fps_idx as float [B,S]
#define OUT_MAIN 24576
#define OUT_FPS  1073152

// ticket-role boundaries (arrival order == topological order; workers are
// readiness-ordered: unit u -> batch u&7, chunk u>>3)
#define T_FPS   0
#define T_TP    8
#define T_WK    1032
#define NBLK    1544

#define SCOPE __HIP_MEMORY_SCOPE_AGENT

typedef float v2f __attribute__((ext_vector_type(2)));

struct Ctrl {
  int ticket;
  int pad0[31];
  int tp_done[8];      // transpose blocks done per batch (128 = all)
};

__device__ __forceinline__ unsigned long long aload64(const unsigned long long* p) {
  return __hip_atomic_load(p, __ATOMIC_RELAXED, SCOPE);
}
__device__ __forceinline__ void astore64(unsigned long long* p, unsigned long long v) {
  __hip_atomic_store(p, v, __ATOMIC_RELAXED, SCOPE);
}

// Packed dual-f32 ops (VOP3P, 64-bit VGPR pairs). Each is exactly two
// independent IEEE f32 ops -> bit-identical to scalar; forced via asm because
// the compiler does not form v_pk_*_f32 from scalar/vector C code here.
__device__ __forceinline__ v2f pk_add(v2f a, v2f b) {
  v2f d; asm("v_pk_add_f32 %0, %1, %2" : "=v"(d) : "v"(a), "v"(b)); return d;
}
__device__ __forceinline__ v2f pk_mul(v2f a, v2f b) {
  v2f d; asm("v_pk_mul_f32 %0, %1, %2" : "=v"(d) : "v"(a), "v"(b)); return d;
}

// DPP-based u64 max reduce step (result accumulates toward lane 63).
template <int CTRL, int RM>
__device__ __forceinline__ unsigned long long dpp_max_step(unsigned long long key) {
  int lo = __builtin_amdgcn_update_dpp(0, (int)(unsigned)(key & 0xFFFFFFFFull), CTRL, RM, 0xF, true);
  int hi = __builtin_amdgcn_update_dpp(0, (int)(unsigned)(key >> 32),           CTRL, RM, 0xF, true);
  unsigned long long o = ((unsigned long long)(unsigned)hi << 32) | (unsigned)lo;
  return o > key ? o : key;
}

// ---------------------------------------------------------------- FPS producer (bit-identical math)
// Update uses v_pk_add/v_pk_mul pairs (2 pts/inst); subtraction as a+(-c) with
// hoisted negated centroid (IEEE-exact). Coord table packed float4 -> single
// ds_read_b128 in the serial tail. Publishes centroids every 32 iters as
// relaxed u64 atomics: nxA=(cx,cy), nxB=(cz, idx+1) (always nonzero).
__device__ void fps_role(int b, const float* __restrict__ xyz,
                         unsigned long long* __restrict__ nxA,
                         unsigned long long* __restrict__ nxB,
                         float* __restrict__ out, void* smem)
{
#pragma clang fp contract(off)
  float4* s_p  = (float4*)smem;                              // [8192] 131072 B
  float4* hist = (float4*)((char*)smem + 131072);            // [1024]  16384 B
  unsigned long long* slots = (unsigned long long*)((char*)smem + 147456);  // [2][8]

  const int tid  = threadIdx.x;
  const int wave = tid >> 6;
  const int lane = tid & 63;
  const float* xb = xyz + (size_t)b * 3 * NPTS;

  v2f px[8], py[8], pz[8], dist[8];
#pragma unroll
  for (int p = 0; p < 8; p++) {
    int ne = (2 * p) * 512 + tid;
    int no = ne + 512;
    px[p] = (v2f){xb[ne], xb[no]};
    py[p] = (v2f){xb[NPTS + ne], xb[NPTS + no]};
    pz[p] = (v2f){xb[2 * NPTS + ne], xb[2 * NPTS + no]};
    dist[p] = (v2f){1e10f, 1e10f};
    s_p[ne] = make_float4(px[p].x, py[p].x, pz[p].x, 0.f);   // LDS coord table
    s_p[no] = make_float4(px[p].y, py[p].y, pz[p].y, 0.f);
  }

  int far = 0;
  float cx = xb[0], cy = xb[NPTS], cz = xb[2 * NPTS];

  for (int t = 0; t < 1024; t++) {
    if (tid == (t & 511))                               // buffer result in LDS
      hist[t] = make_float4(cx, cy, cz, (float)far);

    // progressive publication every 32 centroids (wave 0 only; relaxed atomics)
    if ((t & 31) == 0 && t > 0 && wave == 0 && lane < 32) {
      int tt = t - 32 + lane;
      float4 h = hist[tt];                              // barriered in iters tt..t-1
      int gidx = (b << 10) + tt;
      astore64(&nxA[gidx],
               ((unsigned long long)__float_as_uint(h.x) << 32) | __float_as_uint(h.y));
      astore64(&nxB[gidx],
               ((unsigned long long)__float_as_uint(h.z) << 32) | (unsigned)((int)h.w + 1));
    }

    const float ncx = -cx, ncy = -cy, ncz = -cz;        // hoisted negation (exact)
    const v2f nc2x = (v2f){ncx, ncx};
    const v2f nc2y = (v2f){ncy, ncy};
    const v2f nc2z = (v2f){ncz, ncz};

    // exact per-half update: d = (dx*dx + dy*dy) + dz*dz ; dist = min(dist, d)
    float bd_e = -1.0f, bd_o = -1.0f;
    int   ce   = 0,     co   = 0;
#pragma unroll
    for (int p = 0; p < 8; p++) {
      v2f dx = pk_add(px[p], nc2x);                     // a + (-c) == a - c
      v2f dy = pk_add(py[p], nc2y);
      v2f dz = pk_add(pz[p], nc2z);
      v2f ss = pk_add(pk_mul(dx, dx), pk_mul(dy, dy));
      v2f dd = pk_add(ss, pk_mul(dz, dz));
      float nde = fminf(dist[p].x, dd.x);
      float ndo = fminf(dist[p].y, dd.y);
      dist[p].x = nde;
      dist[p].y = ndo;
      if (nde > bd_e) { bd_e = nde; ce = 2 * p; }       // p ascending => lowest idx on tie
      if (ndo > bd_o) { bd_o = ndo; co = 2 * p + 1; }
    }

    unsigned long long ke =
        ((unsigned long long)__float_as_uint(bd_e) << 32) | (unsigned)(~(unsigned)(ce * 512 + tid));
    unsigned long long ko =
        ((unsigned long long)__float_as_uint(bd_o) << 32) | (unsigned)(~(unsigned)(co * 512 + tid));
    unsigned long long key = ko > ke ? ko : ke;

    key = dpp_max_step<0x111, 0xF>(key);   // row_shr:1
    key = dpp_max_step<0x112, 0xF>(key);   // row_shr:2
    key = dpp_max_step<0x114, 0xF>(key);   // row_shr:4
    key = dpp_max_step<0x118, 0xF>(key);   // row_shr:8
    key = dpp_max_step<0x142, 0xA>(key);   // row_bcast:15 -> rows 1,3
    key = dpp_max_step<0x143, 0xC>(key);   // row_bcast:31 -> rows 2,3
    if (lane == 63) slots[(t & 1) * 8 + wave] = key;
    __syncthreads();                                    // the ONLY barrier per iter

    const unsigned long long* sl = slots + (t & 1) * 8;
    unsigned long long k0 = sl[0], k1 = sl[1], k2 = sl[2], k3 = sl[3];
    unsigned long long k4 = sl[4], k5 = sl[5], k6 = sl[6], k7 = sl[7];
    k0 = k1 > k0 ? k1 : k0;
    k2 = k3 > k2 ? k3 : k2;
    k4 = k5 > k4 ? k5 : k4;
    k6 = k7 > k6 ? k7 : k6;
    k0 = k2 > k0 ? k2 : k0;
    k4 = k6 > k4 ? k6 : k4;
    k0 = k4 > k0 ? k4 : k0;
    int gi = (int)(~(unsigned)(k0 & 0xFFFFFFFFull));
    far = gi;
    float4 c = s_p[gi];                                 // one broadcast ds_read_b128
    cx = c.x; cy = c.y; cz = c.z;
  }
  __syncthreads();

  // final 32 centroids
  if (wave == 0 && lane < 32) {
    int tt = 992 + lane;
    float4 h = hist[tt];
    int gidx = (b << 10) + tt;
    astore64(&nxA[gidx],
             ((unsigned long long)__float_as_uint(h.x) << 32) | __float_as_uint(h.y));
    astore64(&nxB[gidx],
             ((unsigned long long)__float_as_uint(h.z) << 32) | (unsigned)((int)h.w + 1));
  }

  // coalesced endgame writes of the kernel outputs
#pragma unroll
  for (int j = 0; j < 2; j++) {
    int t = j * 512 + tid;
    float4 h = hist[t];
    out[OUT_FPS + b * 1024 + t] = h.w;                  // fps_idx as float
    out[b * 3072 + t]           = h.x;                  // new_xyz [B,3,S]
    out[b * 3072 + 1024 + t]    = h.y;
    out[b * 3072 + 2048 + t]    = h.z;
  }
}

// ---------------------------------------------------------------- transpose [B,64,N] -> [B,N,64]
__device__ void tp_role(int bid, const float* __restrict__ pts, float* __restrict__ ptt,
                        Ctrl* ctrl, void* smem)
{
  float* tile = (float*)smem;            // [64*65]
  const int b  = bid >> 7;
  const int n0 = (bid & 127) * 64;
  const float* pb = pts + (size_t)b * D * NPTS;
#pragma unroll
  for (int i = 0; i < 8; i++) {
    int s = threadIdx.x + i * 512;
    int nl = s & 63, d = s >> 6;
    tile[d * 65 + nl] = pb[(size_t)d * NPTS + n0 + nl];
  }
  __syncthreads();
  float* ob = ptt + ((size_t)b * NPTS + n0) * D;
#pragma unroll
  for (int i = 0; i < 8; i++) {
    int s = threadIdx.x + i * 512;
    int dl = s & 63, nl = s >> 6;
    ob[(size_t)nl * D + dl] = tile[dl * 65 + nl];
  }
  __syncthreads();                                      // drain stores block-wide
  if (threadIdx.x == 0)                                 // RELEASE: waitcnt + wbl2, once
    __hip_atomic_fetch_add(&ctrl->tp_done[b], 1, __ATOMIC_RELEASE, SCOPE);
}

// ---------------------------------------------------------------- persistent worker:
// 16 centroids end-to-end: spin nx flags -> KNN (32 thr/cent) -> weightnet+feat
// (KNN result stays in LDS) -> agg rows (same-block L2) -> 16x128 GEMM+epilogue.
__device__ void worker_role(int u, const float* __restrict__ xyz,
                            const unsigned long long* __restrict__ nxA,
                            const unsigned long long* __restrict__ nxB,
                            const float* __restrict__ ptt,
                            const float* __restrict__ w1, const float* __restrict__ b1,
                            const float* __restrict__ w2, const float* __restrict__ b2,
                            const float* __restrict__ w3, const float* __restrict__ b3,
                            const float* __restrict__ lin_w, const float* __restrict__ lin_b,
                            float* __restrict__ agg, float* __restrict__ out,
                            Ctrl* ctrl, void* smem)
{
  const int tid = threadIdx.x;
  const int b   = u & 7;               // chunk-major: ticket order == readiness order
  const int q   = u >> 3;
  const int c0  = q * 16;
  const int cbase = (b << 10) + c0;

  unsigned long long* s_k = (unsigned long long*)smem;   // [16][545] u64, 69760 B
  float* s_cc = (float*)((char*)smem + 69760);           // [16][4]
  int*   s_nk = (int*)((char*)smem + 70016);             // [16][16]

  // ---- wait for my 16 centroids (relaxed polls; flag embedded in nxB low word)
  if (tid < 16) {
    unsigned long long Bv, Av;
    while ((unsigned)((Bv = aload64(&nxB[cbase + tid])) & 0xFFFFFFFFull) == 0u)
      __builtin_amdgcn_s_sleep(8);
    while ((Av = aload64(&nxA[cbase + tid])) == 0ull)
      __builtin_amdgcn_s_sleep(1);
    s_cc[tid * 4 + 0] = __uint_as_float((unsigned)(Av >> 32));
    s_cc[tid * 4 + 1] = __uint_as_float((unsigned)(Av & 0xFFFFFFFFull));
    s_cc[tid * 4 + 2] = __uint_as_float((unsigned)(Bv >> 32));
  }
  __syncthreads();

  // ---- KNN: 32 threads/cent, 256 pts each, exact reference arithmetic
  {
#pragma clang fp contract(off)
    const int cl    = tid >> 5;
    const int chunk = tid & 31;
    const float* xb = xyz + (size_t)b * 3 * NPTS;
    const float cx = s_cc[cl * 4 + 0];
    const float cy = s_cc[cl * 4 + 1];
    const float cz = s_cc[cl * 4 + 2];

    float nd[16]; int ni[16];
#pragma unroll
    for (int k = 0; k < 16; k++) { nd[k] = 3.4e38f; ni[k] = 0x7FFFFFFF; }

    for (int jj = 0; jj < 256; jj++) {
      int j = jj * 32 + chunk;
      float dx = xb[j] - cx, dy = xb[NPTS + j] - cy, dz = xb[2 * NPTS + j] - cz;
      float d  = (dx * dx + dy * dy) + dz * dz;
      float cv = d; int iv = j;
#pragma unroll
      for (int k = 0; k < 16; k++) {     // branchless sorted insertion (strict <)
        bool sw = cv < nd[k];
        float tv = nd[k]; int ti = ni[k];
        nd[k] = sw ? cv : tv;  ni[k] = sw ? iv : ti;
        cv    = sw ? tv : cv;  iv    = sw ? ti : iv;
      }
    }
#pragma unroll
    for (int k = 0; k < 16; k++)
      s_k[cl * 545 + chunk * 17 + k] =
          ((unsigned long long)__float_as_uint(nd[k]) << 32) | (unsigned)ni[k];
    s_k[cl * 545 + chunk * 17 + 16] = ~0ull;   // sentinel
  }
  __syncthreads();

  if (tid < 16) {                        // merge: 16 rounds of 32-way tournament (u64 min)
    int pos[32];
#pragma unroll
    for (int c = 0; c < 32; c++) pos[c] = 0;
    for (int r = 0; r < 16; r++) {
      unsigned long long bk = ~0ull; int bc = 0;
#pragma unroll
      for (int c = 0; c < 32; c++) {
        unsigned long long kv = s_k[tid * 545 + c * 17 + pos[c]];
        if (kv < bk) { bk = kv; bc = c; }
      }
#pragma unroll
      for (int c = 0; c < 32; c++) pos[c] += (c == bc);
      s_nk[tid * 16 + r] = (int)(bk & 0xFFFFFFFFull);
    }
  }
  if (tid == 0)                          // ptt ready? (relaxed; producer released)
    while (__hip_atomic_load(&ctrl->tp_done[b], __ATOMIC_RELAXED, SCOPE) < 128)
      __builtin_amdgcn_s_sleep(8);
  __syncthreads();

  // ---- feat: 8 waves x 2 iterations (one centroid per wave per iter)
  float* s_wts = (float*)smem;           // [8][272] (s_k region dead)
  float* s_off = s_wts + 8 * 272;        // [8][48]
  const int wv   = tid >> 6;
  const int lane = tid & 63;

  for (int it = 0; it < 2; it++) {
    const int cl2  = it * 8 + wv;        // 0..15
    const int csel = cbase + cl2;
    if (lane < 16) {
      int nk = s_nk[cl2 * 16 + lane];
      const float* xb = xyz + (size_t)b * 3 * NPTS;
      float ox = xb[nk]            - s_cc[cl2 * 4 + 0];
      float oy = xb[NPTS + nk]     - s_cc[cl2 * 4 + 1];
      float oz = xb[2 * NPTS + nk] - s_cc[cl2 * 4 + 2];
      s_off[wv * 48 + lane * 3 + 0] = ox;
      s_off[wv * 48 + lane * 3 + 1] = oy;
      s_off[wv * 48 + lane * 3 + 2] = oz;
      float h1[8], h2[8];
#pragma unroll
      for (int j = 0; j < 8; j++)
        h1[j] = fmaxf(0.f, ox * w1[j] + oy * w1[8 + j] + oz * w1[16 + j] + b1[j]);
#pragma unroll
      for (int j = 0; j < 8; j++) {
        float a = b2[j];
#pragma unroll
        for (int i = 0; i < 8; i++) a = fmaf(h1[i], w2[i * 8 + j], a);
        h2[j] = fmaxf(0.f, a);
      }
#pragma unroll
      for (int w = 0; w < 16; w++) {
        float a = b3[w];
#pragma unroll
        for (int i = 0; i < 8; i++) a = fmaf(h2[i], w3[i * 16 + w], a);
        s_wts[wv * 272 + lane * 17 + w] = fmaxf(0.f, a);
      }
    }
    __syncthreads();

    // gather point-feature channel d = lane for all 16 neighbors
    float f[16];
#pragma unroll
    for (int k = 0; k < 16; k++) {
      int nk = s_nk[cl2 * 16 + k];
      f[k] = ptt[((size_t)b * NPTS + nk) * D + lane];
    }
    float acc[16];
#pragma unroll
    for (int w = 0; w < 16; w++) acc[w] = 0.f;
#pragma unroll
    for (int k = 0; k < 16; k++) {
#pragma unroll
      for (int w = 0; w < 16; w++)
        acc[w] = fmaf(f[k], s_wts[wv * 272 + k * 17 + w], acc[w]);
    }
    float* arow = agg + (size_t)csel * (CIN * WN) + (3 + lane) * 16;
#pragma unroll
    for (int qq = 0; qq < 4; qq++) {
      float4 v = make_float4(acc[4 * qq], acc[4 * qq + 1], acc[4 * qq + 2], acc[4 * qq + 3]);
      *(float4*)(arow + 4 * qq) = v;
    }
    if (lane < 48) {                     // xyz-offset channels c = 0..2
      int c = lane >> 4, w = lane & 15;
      float a = 0.f;
#pragma unroll
      for (int k = 0; k < 16; k++)
        a = fmaf(s_off[wv * 48 + k * 3 + c], s_wts[wv * 272 + k * 17 + w], a);
      agg[(size_t)csel * (CIN * WN) + c * 16 + w] = a;
    }
    __syncthreads();                     // drains agg stores; frees s_wts for next iter
  }

  // ---- GEMM: rows [cbase, cbase+16) x 128 cols, K = 1072 (agg is L2-hot, same block)
  float* a_t = (float*)smem;             // [16][17]
  float* b_t = a_t + 16 * 17;            // [16][128]
  float acc2[2][2] = {};
  for (int kt = 0; kt < 67; kt++) {
    const int k0 = kt * 16;
    if (tid < 256) {
      int r = tid & 15, kk = tid >> 4;
      a_t[kk * 17 + r] = agg[(size_t)(cbase + r) * (CIN * WN) + k0 + kk];
    }
#pragma unroll
    for (int i = 0; i < 4; i++) {
      int idx = tid + i * 512;
      int c = idx & 127, kk = idx >> 7;
      b_t[kk * 128 + c] = lin_w[(size_t)(k0 + kk) * OUTC + c];
    }
    __syncthreads();
#pragma unroll
    for (int kk = 0; kk < 16; kk++) {
      float a0 = a_t[kk * 17 + wv * 2];        // wave-uniform -> LDS broadcast
      float a1 = a_t[kk * 17 + wv * 2 + 1];
      float bv0 = b_t[kk * 128 + lane * 2];    // stride-2 -> conflict-free
      float bv1 = b_t[kk * 128 + lane * 2 + 1];
      acc2[0][0] = fmaf(a0, bv0, acc2[0][0]);
      acc2[0][1] = fmaf(a0, bv1, acc2[0][1]);
      acc2[1][0] = fmaf(a1, bv0, acc2[1][0]);
      acc2[1][1] = fmaf(a1, bv1, acc2[1][1]);
    }
    __syncthreads();
  }
#pragma unroll
  for (int j = 0; j < 2; j++) {
#pragma unroll
    for (int cc = 0; cc < 2; cc++) {
      int ss = c0 + wv * 2 + j;                // centroid index within batch
      int C  = lane * 2 + cc;
      float v = acc2[j][cc] + lin_b[C];
      v = v > 0.f ? v : 0.1f * v;
      out[OUT_MAIN + ((size_t)(b * OUTC + C)) * 1024 + ss] = v;
    }
  }
}

// ---------------------------------------------------------------- mega kernel
__global__ __launch_bounds__(512)
void mega_kernel(const float* __restrict__ xyz, const float* __restrict__ pts,
                 const float* __restrict__ w1, const float* __restrict__ b1,
                 const float* __restrict__ w2, const float* __restrict__ b2,
                 const float* __restrict__ w3, const float* __restrict__ b3,
                 const float* __restrict__ lin_w, const float* __restrict__ lin_b,
                 float* __restrict__ out, unsigned long long* __restrict__ nxA,
                 unsigned long long* __restrict__ nxB,
                 float* __restrict__ ptt, float* __restrict__ agg, Ctrl* ctrl)
{
  __shared__ __align__(16) unsigned long long smem[18448];   // 147584 B union
  __shared__ int s_ticket;
  if (threadIdx.x == 0)
    s_ticket = __hip_atomic_fetch_add(&ctrl->ticket, 1, __ATOMIC_RELAXED, SCOPE);
  __syncthreads();
  const int tk = s_ticket;

  if (tk < T_TP)
    fps_role(tk, xyz, nxA, nxB, out, smem);
  else if (tk < T_WK)
    tp_role(tk - T_TP, pts, ptt, ctrl, smem);
  else
    worker_role(tk - T_WK, xyz, nxA, nxB, ptt, w1, b1, w2, b2, w3, b3,
                lin_w, lin_b, agg, out, ctrl, smem);
}

// ---------------------------------------------------------------- launch
extern "C" void kernel_launch(void* const* d_in, const int* in_sizes, int n_in,
                              void* d_out, int out_size, void* d_ws, size_t ws_size,
                              hipStream_t stream) {
  const float* xyz    = (const float*)d_in[0];
  const float* points = (const float*)d_in[1];
  const float* w1     = (const float*)d_in[2];
  const float* b1     = (const float*)d_in[3];
  const float* w2     = (const float*)d_in[4];
  const float* b2     = (const float*)d_in[5];
  const float* w3     = (const float*)d_in[6];
  const float* b3     = (const float*)d_in[7];
  const float* lin_w  = (const float*)d_in[8];
  const float* lin_b  = (const float*)d_in[9];
  float* out = (float*)d_out;
  char*  ws  = (char*)d_ws;

  Ctrl* ctrl              = (Ctrl*)(ws);                          // 4 KB
  unsigned long long* nxA = (unsigned long long*)(ws + 4096);     // [8192] 64 KB
  unsigned long long* nxB = (unsigned long long*)(ws + 69632);    // [8192] 64 KB
  float* ptt              = (float*)(ws + 1048576);               // [8,8192,64] 16 MiB
  float* agg              = (float*)(ws + 17825792);              // [8192,1072] ~33.5 MiB

  hipMemsetAsync(ws, 0, 135168, stream);   // ctrl + nxA + nxB
  mega_kernel<<<NBLK, 512, 0, stream>>>(xyz, points, w1, b1, w2, b2, w3, b3,
                                        lin_w, lin_b, out, nxA, nxB, ptt, agg, ctrl);
}

// Round 9
// 1278.403 us; speedup vs baseline: 1.0645x; 1.0645x over previous
//
#include <hip/hip_runtime.h>
#include <hip/hip_bf16.h>

#define NPTS   8192
#define NBATCH 8
#define S      1024
#define K      16
#define D      64
#define CIN    67
#define WN     16
#define OUTC   128

// d_out layout (floats): [0,24576) new_xyz [B,3,S]; [24576, 24576+1048576) out [B,128,S];
// [1073152, 1081344) fps_idx as float [B,S]
#define OUT_MAIN 24576
#define OUT_FPS  1073152

// ticket-role boundaries (arrival order == topological order; workers are
// readiness-ordered: unit u -> batch u&7, chunk u>>3)
#define T_FPS   0
#define T_TP    8
#define T_WK    1032
#define NBLK    1544

#define SCOPE __HIP_MEMORY_SCOPE_AGENT

typedef float v2f __attribute__((ext_vector_type(2)));

struct Ctrl {
  int ticket;
  int pad0[31];
  int tp_done[8];      // transpose blocks done per batch (128 = all)
  int pad1[24];
  int prog[8];         // FPS publication progress (centroids) per batch
};

__device__ __forceinline__ unsigned long long aload64(const unsigned long long* p) {
  return __hip_atomic_load(p, __ATOMIC_RELAXED, SCOPE);
}
__device__ __forceinline__ void astore64(unsigned long long* p, unsigned long long v) {
  __hip_atomic_store(p, v, __ATOMIC_RELAXED, SCOPE);
}

// Block barrier that waits only on LDS ops (no vmcnt drain): the FPS loop's
// only global ops are fire-and-forget relaxed atomic stores; draining them at
// every barrier (what __syncthreads emits) stalls all waves on fabric latency.
__device__ __forceinline__ void barrier_lgkm() {
  asm volatile("s_waitcnt lgkmcnt(0)\n\ts_barrier" ::: "memory");
}

// DPP-based u64 max reduce step (result accumulates toward lane 63).
template <int CTRL, int RM>
__device__ __forceinline__ unsigned long long dpp_max_step(unsigned long long key) {
  int lo = __builtin_amdgcn_update_dpp(0, (int)(unsigned)(key & 0xFFFFFFFFull), CTRL, RM, 0xF, true);
  int hi = __builtin_amdgcn_update_dpp(0, (int)(unsigned)(key >> 32),           CTRL, RM, 0xF, true);
  unsigned long long o = ((unsigned long long)(unsigned)hi << 32) | (unsigned)lo;
  return o > key ? o : key;
}

// ---------------------------------------------------------------- FPS producer (bit-identical math)
// Publishes centroids every 32 iters as relaxed u64 atomics (nxA=(cx,cy),
// nxB=(cz, idx+1), always nonzero -> flag embedded in data) plus a per-batch
// progress counter. In-loop barriers are lgkm-only: publication stores are
// never drained inside the loop.
__device__ void fps_role(int b, const float* __restrict__ xyz,
                         unsigned long long* __restrict__ nxA,
                         unsigned long long* __restrict__ nxB,
                         float* __restrict__ out, Ctrl* ctrl, void* smem)
{
#pragma clang fp contract(off)
  float* s_x = (float*)smem;                    // [8192]
  float* s_y = s_x + NPTS;
  float* s_z = s_y + NPTS;
  float4* hist = (float4*)((char*)smem + 98304);            // [1024]
  unsigned long long* slots = (unsigned long long*)((char*)smem + 114688);  // [2][8]

  const int tid  = threadIdx.x;
  const int wave = tid >> 6;
  const int lane = tid & 63;
  const float* xb = xyz + (size_t)b * 3 * NPTS;

  v2f px[8], py[8], pz[8], dist[8];
#pragma unroll
  for (int p = 0; p < 8; p++) {
    int ne = (2 * p) * 512 + tid;
    int no = ne + 512;
    px[p] = (v2f){xb[ne], xb[no]};
    py[p] = (v2f){xb[NPTS + ne], xb[NPTS + no]};
    pz[p] = (v2f){xb[2 * NPTS + ne], xb[2 * NPTS + no]};
    dist[p] = (v2f){1e10f, 1e10f};
    s_x[ne] = px[p].x; s_x[no] = px[p].y;       // LDS copy for coord re-fetch
    s_y[ne] = py[p].x; s_y[no] = py[p].y;
    s_z[ne] = pz[p].x; s_z[no] = pz[p].y;
  }

  int far = 0;
  float cx = xb[0], cy = xb[NPTS], cz = xb[2 * NPTS];

  for (int t = 0; t < 1024; t++) {
    if (tid == (t & 511))                               // buffer result in LDS
      hist[t] = make_float4(cx, cy, cz, (float)far);

    // progressive publication every 32 centroids (wave 0 only; relaxed atomics,
    // fire-and-forget: lgkm-only barriers never wait on them)
    if ((t & 31) == 0 && t > 0 && wave == 0 && lane < 32) {
      int tt = t - 32 + lane;
      float4 h = hist[tt];                              // barriered in iters tt..t-1
      int gidx = (b << 10) + tt;
      astore64(&nxA[gidx],
               ((unsigned long long)__float_as_uint(h.x) << 32) | __float_as_uint(h.y));
      astore64(&nxB[gidx],
               ((unsigned long long)__float_as_uint(h.z) << 32) | (unsigned)((int)h.w + 1));
      if (lane == 0)
        __hip_atomic_store(&ctrl->prog[b], t, __ATOMIC_RELAXED, SCOPE);
    }

    const v2f c2x = (v2f){cx, cx}, c2y = (v2f){cy, cy}, c2z = (v2f){cz, cz};

    // exact per-half update: d = (dx*dx + dy*dy) + dz*dz ; dist = min(dist, d)
    float bd_e = -1.0f, bd_o = -1.0f;
    int   ce   = 0,     co   = 0;
#pragma unroll
    for (int p = 0; p < 8; p++) {
      v2f dx = px[p] - c2x, dy = py[p] - c2y, dz = pz[p] - c2z;
      v2f d  = (dx * dx + dy * dy) + dz * dz;
      float nde = fminf(dist[p].x, d.x);
      float ndo = fminf(dist[p].y, d.y);
      dist[p].x = nde;
      dist[p].y = ndo;
      if (nde > bd_e) { bd_e = nde; ce = 2 * p; }       // p ascending => lowest idx on tie
      if (ndo > bd_o) { bd_o = ndo; co = 2 * p + 1; }
    }

    unsigned long long ke =
        ((unsigned long long)__float_as_uint(bd_e) << 32) | (unsigned)(~(unsigned)(ce * 512 + tid));
    unsigned long long ko =
        ((unsigned long long)__float_as_uint(bd_o) << 32) | (unsigned)(~(unsigned)(co * 512 + tid));
    unsigned long long key = ko > ke ? ko : ke;

    key = dpp_max_step<0x111, 0xF>(key);   // row_shr:1
    key = dpp_max_step<0x112, 0xF>(key);   // row_shr:2
    key = dpp_max_step<0x114, 0xF>(key);   // row_shr:4
    key = dpp_max_step<0x118, 0xF>(key);   // row_shr:8
    key = dpp_max_step<0x142, 0xA>(key);   // row_bcast:15 -> rows 1,3
    key = dpp_max_step<0x143, 0xC>(key);   // row_bcast:31 -> rows 2,3
    if (lane == 63) slots[(t & 1) * 8 + wave] = key;
    barrier_lgkm();                                     // lgkm-only: no vmcnt drain

    const unsigned long long* sl = slots + (t & 1) * 8;
    unsigned long long k0 = sl[0], k1 = sl[1], k2 = sl[2], k3 = sl[3];
    unsigned long long k4 = sl[4], k5 = sl[5], k6 = sl[6], k7 = sl[7];
    k0 = k1 > k0 ? k1 : k0;
    k2 = k3 > k2 ? k3 : k2;
    k4 = k5 > k4 ? k5 : k4;
    k6 = k7 > k6 ? k7 : k6;
    k0 = k2 > k0 ? k2 : k0;
    k4 = k6 > k4 ? k6 : k4;
    k0 = k4 > k0 ? k4 : k0;
    int gi = (int)(~(unsigned)(k0 & 0xFFFFFFFFull));
    far = gi;
    cx = s_x[gi]; cy = s_y[gi]; cz = s_z[gi];
  }
  __syncthreads();                                      // full drain before endgame

  // final 32 centroids + progress
  if (wave == 0 && lane < 32) {
    int tt = 992 + lane;
    float4 h = hist[tt];
    int gidx = (b << 10) + tt;
    astore64(&nxA[gidx],
             ((unsigned long long)__float_as_uint(h.x) << 32) | __float_as_uint(h.y));
    astore64(&nxB[gidx],
             ((unsigned long long)__float_as_uint(h.z) << 32) | (unsigned)((int)h.w + 1));
    if (lane == 0)
      __hip_atomic_store(&ctrl->prog[b], 1024, __ATOMIC_RELAXED, SCOPE);
  }

  // coalesced endgame writes of the kernel outputs
#pragma unroll
  for (int j = 0; j < 2; j++) {
    int t = j * 512 + tid;
    float4 h = hist[t];
    out[OUT_FPS + b * 1024 + t] = h.w;                  // fps_idx as float
    out[b * 3072 + t]           = h.x;                  // new_xyz [B,3,S]
    out[b * 3072 + 1024 + t]    = h.y;
    out[b * 3072 + 2048 + t]    = h.z;
  }
}

// ---------------------------------------------------------------- transpose [B,64,N] -> [B,N,64]
__device__ void tp_role(int bid, const float* __restrict__ pts, float* __restrict__ ptt,
                        Ctrl* ctrl, void* smem)
{
  float* tile = (float*)smem;            // [64*65]
  const int b  = bid >> 7;
  const int n0 = (bid & 127) * 64;
  const float* pb = pts + (size_t)b * D * NPTS;
#pragma unroll
  for (int i = 0; i < 8; i++) {
    int s = threadIdx.x + i * 512;
    int nl = s & 63, d = s >> 6;
    tile[d * 65 + nl] = pb[(size_t)d * NPTS + n0 + nl];
  }
  __syncthreads();
  float* ob = ptt + ((size_t)b * NPTS + n0) * D;
#pragma unroll
  for (int i = 0; i < 8; i++) {
    int s = threadIdx.x + i * 512;
    int dl = s & 63, nl = s >> 6;
    ob[(size_t)nl * D + dl] = tile[dl * 65 + nl];
  }
  __syncthreads();                                      // drain stores block-wide
  if (threadIdx.x == 0)                                 // RELEASE: waitcnt + wbl2, once
    __hip_atomic_fetch_add(&ctrl->tp_done[b], 1, __ATOMIC_RELEASE, SCOPE);
}

// ---------------------------------------------------------------- persistent worker:
// 16 centroids end-to-end: wait on per-batch progress counter (1 poller lane,
// deficit-scaled s_sleep) -> one-shot guarded nx reads -> KNN (32 thr/cent) ->
// weightnet+feat (KNN result stays in LDS) -> agg rows -> 16x128 GEMM+epilogue.
__device__ void worker_role(int u, const float* __restrict__ xyz,
                            const unsigned long long* __restrict__ nxA,
                            const unsigned long long* __restrict__ nxB,
                            const float* __restrict__ ptt,
                            const float* __restrict__ w1, const float* __restrict__ b1,
                            const float* __restrict__ w2, const float* __restrict__ b2,
                            const float* __restrict__ w3, const float* __restrict__ b3,
                            const float* __restrict__ lin_w, const float* __restrict__ lin_b,
                            float* __restrict__ agg, float* __restrict__ out,
                            Ctrl* ctrl, void* smem)
{
  const int tid = threadIdx.x;
  const int b   = u & 7;               // chunk-major: ticket order == readiness order
  const int q   = u >> 3;
  const int c0  = q * 16;
  const int cbase = (b << 10) + c0;

  unsigned long long* s_k = (unsigned long long*)smem;   // [16][545] u64, 69760 B
  float* s_cc = (float*)((char*)smem + 69760);           // [16][4]
  int*   s_nk = (int*)((char*)smem + 70016);             // [16][16]

  // ---- wait: single poller on per-batch progress counter, backoff sleep
  if (tid == 0) {
    const int need = c0 + 16;
    int p;
    while ((p = __hip_atomic_load(&ctrl->prog[b], __ATOMIC_RELAXED, SCOPE)) < need) {
      if (need - p > 64) __builtin_amdgcn_s_sleep(127);
      else               __builtin_amdgcn_s_sleep(16);
    }
  }
  __syncthreads();

  // one-shot guarded reads (prog is a hint; nx flags are the real guard)
  if (tid < 16) {
    unsigned long long Bv, Av;
    while ((unsigned)((Bv = aload64(&nxB[cbase + tid])) & 0xFFFFFFFFull) == 0u)
      __builtin_amdgcn_s_sleep(2);
    while ((Av = aload64(&nxA[cbase + tid])) == 0ull)
      __builtin_amdgcn_s_sleep(1);
    s_cc[tid * 4 + 0] = __uint_as_float((unsigned)(Av >> 32));
    s_cc[tid * 4 + 1] = __uint_as_float((unsigned)(Av & 0xFFFFFFFFull));
    s_cc[tid * 4 + 2] = __uint_as_float((unsigned)(Bv >> 32));
  }
  __syncthreads();

  // ---- KNN: 32 threads/cent, 256 pts each, exact reference arithmetic
  {
#pragma clang fp contract(off)
    const int cl    = tid >> 5;
    const int chunk = tid & 31;
    const float* xb = xyz + (size_t)b * 3 * NPTS;
    const float cx = s_cc[cl * 4 + 0];
    const float cy = s_cc[cl * 4 + 1];
    const float cz = s_cc[cl * 4 + 2];

    float nd[16]; int ni[16];
#pragma unroll
    for (int k = 0; k < 16; k++) { nd[k] = 3.4e38f; ni[k] = 0x7FFFFFFF; }

    for (int jj = 0; jj < 256; jj++) {
      int j = jj * 32 + chunk;
      float dx = xb[j] - cx, dy = xb[NPTS + j] - cy, dz = xb[2 * NPTS + j] - cz;
      float d  = (dx * dx + dy * dy) + dz * dz;
      float cv = d; int iv = j;
#pragma unroll
      for (int k = 0; k < 16; k++) {     // branchless sorted insertion (strict <)
        bool sw = cv < nd[k];
        float tv = nd[k]; int ti = ni[k];
        nd[k] = sw ? cv : tv;  ni[k] = sw ? iv : ti;
        cv    = sw ? tv : cv;  iv    = sw ? ti : iv;
      }
    }
#pragma unroll
    for (int k = 0; k < 16; k++)
      s_k[cl * 545 + chunk * 17 + k] =
          ((unsigned long long)__float_as_uint(nd[k]) << 32) | (unsigned)ni[k];
    s_k[cl * 545 + chunk * 17 + 16] = ~0ull;   // sentinel
  }
  __syncthreads();

  if (tid < 16) {                        // merge: 16 rounds of 32-way tournament (u64 min)
    int pos[32];
#pragma unroll
    for (int c = 0; c < 32; c++) pos[c] = 0;
    for (int r = 0; r < 16; r++) {
      unsigned long long bk = ~0ull; int bc = 0;
#pragma unroll
      for (int c = 0; c < 32; c++) {
        unsigned long long kv = s_k[tid * 545 + c * 17 + pos[c]];
        if (kv < bk) { bk = kv; bc = c; }
      }
#pragma unroll
      for (int c = 0; c < 32; c++) pos[c] += (c == bc);
      s_nk[tid * 16 + r] = (int)(bk & 0xFFFFFFFFull);
    }
  }
  if (tid == 0)                          // ptt ready? (relaxed; producer released)
    while (__hip_atomic_load(&ctrl->tp_done[b], __ATOMIC_RELAXED, SCOPE) < 128)
      __builtin_amdgcn_s_sleep(8);
  __syncthreads();

  // ---- feat: 8 waves x 2 iterations (one centroid per wave per iter)
  float* s_wts = (float*)smem;           // [8][272] (s_k region dead)
  float* s_off = s_wts + 8 * 272;        // [8][48]
  const int wv   = tid >> 6;
  const int lane = tid & 63;

  for (int it = 0; it < 2; it++) {
    const int cl2  = it * 8 + wv;        // 0..15
    const int csel = cbase + cl2;
    if (lane < 16) {
      int nk = s_nk[cl2 * 16 + lane];
      const float* xb = xyz + (size_t)b * 3 * NPTS;
      float ox = xb[nk]            - s_cc[cl2 * 4 + 0];
      float oy = xb[NPTS + nk]     - s_cc[cl2 * 4 + 1];
      float oz = xb[2 * NPTS + nk] - s_cc[cl2 * 4 + 2];
      s_off[wv * 48 + lane * 3 + 0] = ox;
      s_off[wv * 48 + lane * 3 + 1] = oy;
      s_off[wv * 48 + lane * 3 + 2] = oz;
      float h1[8], h2[8];
#pragma unroll
      for (int j = 0; j < 8; j++)
        h1[j] = fmaxf(0.f, ox * w1[j] + oy * w1[8 + j] + oz * w1[16 + j] + b1[j]);
#pragma unroll
      for (int j = 0; j < 8; j++) {
        float a = b2[j];
#pragma unroll
        for (int i = 0; i < 8; i++) a = fmaf(h1[i], w2[i * 8 + j], a);
        h2[j] = fmaxf(0.f, a);
      }
#pragma unroll
      for (int w = 0; w < 16; w++) {
        float a = b3[w];
#pragma unroll
        for (int i = 0; i < 8; i++) a = fmaf(h2[i], w3[i * 16 + w], a);
        s_wts[wv * 272 + lane * 17 + w] = fmaxf(0.f, a);
      }
    }
    __syncthreads();

    // gather point-feature channel d = lane for all 16 neighbors
    float f[16];
#pragma unroll
    for (int k = 0; k < 16; k++) {
      int nk = s_nk[cl2 * 16 + k];
      f[k] = ptt[((size_t)b * NPTS + nk) * D + lane];
    }
    float acc[16];
#pragma unroll
    for (int w = 0; w < 16; w++) acc[w] = 0.f;
#pragma unroll
    for (int k = 0; k < 16; k++) {
#pragma unroll
      for (int w = 0; w < 16; w++)
        acc[w] = fmaf(f[k], s_wts[wv * 272 + k * 17 + w], acc[w]);
    }
    float* arow = agg + (size_t)csel * (CIN * WN) + (3 + lane) * 16;
#pragma unroll
    for (int qq = 0; qq < 4; qq++) {
      float4 v = make_float4(acc[4 * qq], acc[4 * qq + 1], acc[4 * qq + 2], acc[4 * qq + 3]);
      *(float4*)(arow + 4 * qq) = v;
    }
    if (lane < 48) {                     // xyz-offset channels c = 0..2
      int c = lane >> 4, w = lane & 15;
      float a = 0.f;
#pragma unroll
      for (int k = 0; k < 16; k++)
        a = fmaf(s_off[wv * 48 + k * 3 + c], s_wts[wv * 272 + k * 17 + w], a);
      agg[(size_t)csel * (CIN * WN) + c * 16 + w] = a;
    }
    __syncthreads();                     // drains agg stores; frees s_wts for next iter
  }

  // ---- GEMM: rows [cbase, cbase+16) x 128 cols, K = 1072 (agg is L2-hot, same block)
  float* a_t = (float*)smem;             // [16][17]
  float* b_t = a_t + 16 * 17;            // [16][128]
  float acc2[2][2] = {};
  for (int kt = 0; kt < 67; kt++) {
    const int k0 = kt * 16;
    if (tid < 256) {
      int r = tid & 15, kk = tid >> 4;
      a_t[kk * 17 + r] = agg[(size_t)(cbase + r) * (CIN * WN) + k0 + kk];
    }
#pragma unroll
    for (int i = 0; i < 4; i++) {
      int idx = tid + i * 512;
      int c = idx & 127, kk = idx >> 7;
      b_t[kk * 128 + c] = lin_w[(size_t)(k0 + kk) * OUTC + c];
    }
    __syncthreads();
#pragma unroll
    for (int kk = 0; kk < 16; kk++) {
      float a0 = a_t[kk * 17 + wv * 2];        // wave-uniform -> LDS broadcast
      float a1 = a_t[kk * 17 + wv * 2 + 1];
      float bv0 = b_t[kk * 128 + lane * 2];    // stride-2 -> conflict-free
      float bv1 = b_t[kk * 128 + lane * 2 + 1];
      acc2[0][0] = fmaf(a0, bv0, acc2[0][0]);
      acc2[0][1] = fmaf(a0, bv1, acc2[0][1]);
      acc2[1][0] = fmaf(a1, bv0, acc2[1][0]);
      acc2[1][1] = fmaf(a1, bv1, acc2[1][1]);
    }
    __syncthreads();
  }
#pragma unroll
  for (int j = 0; j < 2; j++) {
#pragma unroll
    for (int cc = 0; cc < 2; cc++) {
      int ss = c0 + wv * 2 + j;                // centroid index within batch
      int C  = lane * 2 + cc;
      float v = acc2[j][cc] + lin_b[C];
      v = v > 0.f ? v : 0.1f * v;
      out[OUT_MAIN + ((size_t)(b * OUTC + C)) * 1024 + ss] = v;
    }
  }
}

// ---------------------------------------------------------------- mega kernel
__global__ __launch_bounds__(512)
void mega_kernel(const float* __restrict__ xyz, const float* __restrict__ pts,
                 const float* __restrict__ w1, const float* __restrict__ b1,
                 const float* __restrict__ w2, const float* __restrict__ b2,
                 const float* __restrict__ w3, const float* __restrict__ b3,
                 const float* __restrict__ lin_w, const float* __restrict__ lin_b,
                 float* __restrict__ out, unsigned long long* __restrict__ nxA,
                 unsigned long long* __restrict__ nxB,
                 float* __restrict__ ptt, float* __restrict__ agg, Ctrl* ctrl)
{
  __shared__ __align__(16) unsigned long long smem[14400];   // 115200 B union
  __shared__ int s_ticket;
  if (threadIdx.x == 0)
    s_ticket = __hip_atomic_fetch_add(&ctrl->ticket, 1, __ATOMIC_RELAXED, SCOPE);
  __syncthreads();
  const int tk = s_ticket;

  if (tk < T_TP)
    fps_role(tk, xyz, nxA, nxB, out, ctrl, smem);
  else if (tk < T_WK)
    tp_role(tk - T_TP, pts, ptt, ctrl, smem);
  else
    worker_role(tk - T_WK, xyz, nxA, nxB, ptt, w1, b1, w2, b2, w3, b3,
                lin_w, lin_b, agg, out, ctrl, smem);
}

// ---------------------------------------------------------------- launch
extern "C" void kernel_launch(void* const* d_in, const int* in_sizes, int n_in,
                              void* d_out, int out_size, void* d_ws, size_t ws_size,
                              hipStream_t stream) {
  const float* xyz    = (const float*)d_in[0];
  const float* points = (const float*)d_in[1];
  const float* w1     = (const float*)d_in[2];
  const float* b1     = (const float*)d_in[3];
  const float* w2     = (const float*)d_in[4];
  const float* b2     = (const float*)d_in[5];
  const float* w3     = (const float*)d_in[6];
  const float* b3     = (const float*)d_in[7];
  const float* lin_w  = (const float*)d_in[8];
  const float* lin_b  = (const float*)d_in[9];
  float* out = (float*)d_out;
  char*  ws  = (char*)d_ws;

  Ctrl* ctrl              = (Ctrl*)(ws);                          // 4 KB
  unsigned long long* nxA = (unsigned long long*)(ws + 4096);     // [8192] 64 KB
  unsigned long long* nxB = (unsigned long long*)(ws + 69632);    // [8192] 64 KB
  float* ptt              = (float*)(ws + 1048576);               // [8,8192,64] 16 MiB
  float* agg              = (float*)(ws + 17825792);              // [8192,1072] ~33.5 MiB

  hipMemsetAsync(ws, 0, 135168, stream);   // ctrl + nxA + nxB
  mega_kernel<<<NBLK, 512, 0, stream>>>(xyz, points, w1, b1, w2, b2, w3, b3,
                                        lin_w, lin_b, out, nxA, nxB, ptt, agg, ctrl);
}